// Round 7
// baseline (598.499 us; speedup 1.0000x reference)
//
#include <hip/hip_runtime.h>
#include <hip/hip_fp16.h>

#define NN 100000
#define NE 1600000
#define DD 128
#define NB 500           // bins
#define NPB 200          // nodes per bin (NB*NPB == NN)
#define RSEG 8           // replica cursors per bin
#define SEGCAP 640       // per-replica capacity (mean 400, +12 sigma)
#define SEGTOT (NB*RSEG)
#define STAGE_CAP 4096   // per-bin edge stage (mean 3200, +15 sigma)
#define FRAG_ELEMS 16384 // one 128x128 matrix in fragment order

typedef __attribute__((ext_vector_type(8))) _Float16 half8;
typedef __attribute__((ext_vector_type(4))) float f32x4;

// ---------------- cast x (fp32) -> f16 ----------------
__global__ void k_xcast(const float* __restrict__ x, _Float16* __restrict__ xh) {
    int t = blockIdx.x * 256 + threadIdx.x;        // NN*DD/8 = 1.6M threads
    const float* p = x + (size_t)t * 8;
    float4 v0 = *(const float4*)p;
    float4 v1 = *(const float4*)(p + 4);
    half8 o = { (_Float16)v0.x, (_Float16)v0.y, (_Float16)v0.z, (_Float16)v0.w,
                (_Float16)v1.x, (_Float16)v1.y, (_Float16)v1.z, (_Float16)v1.w };
    *(half8*)(xh + (size_t)t * 8) = o;
}

// ---------------- bin phase A: append packed (local_dst,src) to bin segments ----------------
// writes within a segment are sequential -> full 64B lines, no writeback inflation.
__global__ void k_binA(const int* __restrict__ src, const int* __restrict__ dst,
                       int* __restrict__ segcnt, unsigned int* __restrict__ binbuf) {
    int e = blockIdx.x * 256 + threadIdx.x;
    if (e >= NE) return;
    int s = src[e];
    int d = dst[e];
    int bin = d / NPB;
    int local = d - bin * NPB;
    int seg = bin * RSEG + (e & (RSEG - 1));
    int p = atomicAdd(&segcnt[seg], 1);
    if (p < SEGCAP) binbuf[(size_t)seg * SEGCAP + p] = (unsigned)s | ((unsigned)local << 17);
}

// ---------------- bin phase B: per-bin LDS sort -> exact CSR (coalesced writes) ----------------
__global__ __launch_bounds__(256) void k_binB(const int* __restrict__ segcnt,
                                              const unsigned int* __restrict__ binbuf,
                                              int* __restrict__ offs, int* __restrict__ csr) {
    __shared__ int red[256];
    __shared__ int lcnt[NPB], lofs[NPB], lcur[NPB];
    __shared__ unsigned int stage[STAGE_CAP];
    int bin = blockIdx.x;
    int t = threadIdx.x;
    int lim = bin * RSEG;

    // base = edges in all earlier bins (clamped counts)
    int part = 0;
    for (int i = t; i < lim; i += 256) {
        int c = segcnt[i];
        part += (c > SEGCAP ? SEGCAP : c);
    }
    red[t] = part;
    if (t < NPB) lcnt[t] = 0;
    __syncthreads();
    for (int d = 128; d; d >>= 1) {
        if (t < d) red[t] += red[t + d];
        __syncthreads();
    }
    int base = red[0];
    __syncthreads();

    int m[RSEG];
#pragma unroll
    for (int k = 0; k < RSEG; ++k) {
        int c = segcnt[lim + k];
        m[k] = c > SEGCAP ? SEGCAP : c;
    }

    // pass 1: local degree count
#pragma unroll
    for (int k = 0; k < RSEG; ++k) {
        const unsigned int* sb = binbuf + (size_t)(lim + k) * SEGCAP;
        for (int i = t; i < m[k]; i += 256) atomicAdd(&lcnt[sb[i] >> 17], 1);
    }
    __syncthreads();

    // exclusive scan of lcnt
    int v = (t < NPB) ? lcnt[t] : 0;
    red[t] = v;
    __syncthreads();
    for (int d = 1; d < 256; d <<= 1) {
        int u = (t >= d) ? red[t - d] : 0;
        __syncthreads();
        red[t] += u;
        __syncthreads();
    }
    if (t < NPB) { lofs[t] = red[t] - v; lcur[t] = 0; }
    int mtot = red[255];
    __syncthreads();

    // write offsets
    if (t < NPB) offs[bin * NPB + t] = base + lofs[t];
    if (bin == NB - 1 && t == 0) offs[NN] = base + mtot;

    // pass 2: place src into LDS stage at CSR position
#pragma unroll
    for (int k = 0; k < RSEG; ++k) {
        const unsigned int* sb = binbuf + (size_t)(lim + k) * SEGCAP;
        for (int i = t; i < m[k]; i += 256) {
            unsigned int p = sb[i];
            int local = p >> 17;
            int q = atomicAdd(&lcur[local], 1);
            int pos = lofs[local] + q;
            if (pos < STAGE_CAP) stage[pos] = p & 0x1FFFFu;
        }
    }
    __syncthreads();

    // coalesced flush
    int lim2 = mtot > STAGE_CAP ? STAGE_CAP : mtot;
    for (int i = t; i < lim2; i += 256) csr[base + i] = (int)stage[i];
}

// ---------------- weight prep: transpose + f16 hi/lo split into MFMA B-frag order ----
__global__ __launch_bounds__(256) void k_wprep(const float* __restrict__ W0,
                                               const float* __restrict__ W1,
                                               const float* __restrict__ W2,
                                               const float* __restrict__ W3,
                                               const float* __restrict__ W4,
                                               const float* __restrict__ W5,
                                               _Float16* __restrict__ out) {
    int mat = blockIdx.x >> 6;                       // 64 blocks per matrix
    int e = (blockIdx.x & 63) * 256 + threadIdx.x;   // 0..16383
    const float* W = (mat == 0) ? W0 : (mat == 1) ? W1 : (mat == 2) ? W2
                   : (mat == 3) ? W3 : (mat == 4) ? W4 : W5;
    int j = e & 7;
    int lane = (e >> 3) & 63;
    int ct = (e >> 9) & 7;
    int kt = e >> 12;
    int k = kt * 32 + (lane >> 4) * 8 + j;
    int n = ct * 16 + (lane & 15);
    float v = W[k * 128 + n];
    _Float16 hi = (_Float16)v;
    _Float16 lo = (_Float16)(v - (float)hi);
    _Float16* mb = out + (size_t)mat * 2 * FRAG_ELEMS;
    mb[e] = hi;
    mb[FRAG_ELEMS + e] = lo;
}

// ---------------- gather-aggregate (f16 rows, exact CSR) ----------------
// one wave per node; quarter q owns edge (i+q); lane covers 8 f16 of the row.
__global__ __launch_bounds__(256) void k_agg(const _Float16* __restrict__ h,
                                             const int* __restrict__ offs,
                                             const int* __restrict__ csr,
                                             _Float16* __restrict__ mean) {
    int node = blockIdx.x * 4 + (threadIdx.x >> 6);
    if (node >= NN) return;
    int lane = threadIdx.x & 63;
    int q = lane >> 4;
    int col = (lane & 15) * 8;
    int beg = offs[node];
    int end = offs[node + 1];
    int n = end - beg;
    const int* b = csr + beg;
    float a[8] = {};
    int i = 0;
    for (; i + 8 <= n; i += 8) {
        int s0 = b[i + q];
        int s1 = b[i + 4 + q];
        half8 v0 = *(const half8*)(h + (size_t)s0 * DD + col);
        half8 v1 = *(const half8*)(h + (size_t)s1 * DD + col);
#pragma unroll
        for (int j = 0; j < 8; ++j) a[j] += (float)v0[j] + (float)v1[j];
    }
    if (i + 4 <= n) {
        int s0 = b[i + q];
        half8 v0 = *(const half8*)(h + (size_t)s0 * DD + col);
#pragma unroll
        for (int j = 0; j < 8; ++j) a[j] += (float)v0[j];
        i += 4;
    }
    if (i + q < n) {
        int s = b[i + q];
        half8 v = *(const half8*)(h + (size_t)s * DD + col);
#pragma unroll
        for (int j = 0; j < 8; ++j) a[j] += (float)v[j];
    }
#pragma unroll
    for (int j = 0; j < 8; ++j) {
        a[j] += __shfl_xor(a[j], 16);
        a[j] += __shfl_xor(a[j], 32);
    }
    if (q == 0) {
        float di = 1.0f / (float)(n > 1 ? n : 1);
        half8 o;
#pragma unroll
        for (int j = 0; j < 8; ++j) o[j] = (_Float16)(a[j] * di);
        *(half8*)(mean + (size_t)node * DD + col) = o;
    }
}

// ---------------- fused transform: out = act( mean@Wn + h@Ws + b ) ----------------
// A f16, B f16 hi+lo (fp32-grade weights), fp32 accumulate. No LDS, no barriers.
__global__ __launch_bounds__(256) void k_gemm(
    const _Float16* __restrict__ meanp, const _Float16* __restrict__ hin,
    const _Float16* __restrict__ wf,   // [WnHi|WnLo|WsHi|WsLo] x 16384
    const float* __restrict__ bias,
    _Float16* __restrict__ outh, float* __restrict__ outf) {

    int t = threadIdx.x;
    int wave = t >> 6;
    int lane = t & 63;
    int m16 = lane & 15;
    int kg = lane >> 4;
    int rowA = blockIdx.x * 64 + wave * 16 + m16;
    if (rowA >= NN) rowA = NN - 1;       // clamp (store is guarded)

    f32x4 acc[8] = {};

#pragma unroll
    for (int s = 0; s < 2; ++s) {
        const _Float16* Whi = wf + s * 2 * FRAG_ELEMS;
        const _Float16* Wlo = Whi + FRAG_ELEMS;
        const _Float16* Ap = (s ? hin : meanp) + (size_t)rowA * DD;
#pragma unroll
        for (int kt = 0; kt < 4; ++kt) {
            half8 a = *(const half8*)(Ap + kt * 32 + kg * 8);
#pragma unroll
            for (int ct = 0; ct < 8; ++ct) {
                int off = ((kt * 8 + ct) * 64 + lane) * 8;
                half8 bh = *(const half8*)(Whi + off);
                half8 bl = *(const half8*)(Wlo + off);
                acc[ct] = __builtin_amdgcn_mfma_f32_16x16x32_f16(a, bh, acc[ct], 0, 0, 0);
                acc[ct] = __builtin_amdgcn_mfma_f32_16x16x32_f16(a, bl, acc[ct], 0, 0, 0);
            }
        }
    }

    // epilogue: C layout col=lane&15, row=(lane>>4)*4+reg
    int rbase = blockIdx.x * 64 + wave * 16 + kg * 4;
    if (outh) {
#pragma unroll
        for (int ct = 0; ct < 8; ++ct) {
            int col = ct * 16 + m16;
            float bv = bias[col];
#pragma unroll
            for (int i = 0; i < 4; ++i) {
                int r = rbase + i;
                if (r < NN)
                    outh[(size_t)r * DD + col] = (_Float16)fmaxf(acc[ct][i] + bv, 0.0f);
            }
        }
    } else {
#pragma unroll
        for (int ct = 0; ct < 8; ++ct) {
            int col = ct * 16 + m16;
            float bv = bias[col];
#pragma unroll
            for (int i = 0; i < 4; ++i) {
                int r = rbase + i;
                if (r < NN)
                    outf[(size_t)r * DD + col] = acc[ct][i] + bv;
            }
        }
    }
}

// ---------------- fc (128->16) + log_softmax (fp32) ----------------
__global__ __launch_bounds__(256) void k_fc(const float* __restrict__ emb,
                                            const float* __restrict__ Wfc,
                                            const float* __restrict__ bfc,
                                            float* __restrict__ out) {
    __shared__ float se[16 * 128];
    __shared__ float swt[128 * 16];
    int t = threadIdx.x;
    int nb = blockIdx.x * 16;
    int idx = t * 8;
    *(float4*)(se + idx)      = *(const float4*)(emb + (size_t)nb * 128 + idx);
    *(float4*)(se + idx + 4)  = *(const float4*)(emb + (size_t)nb * 128 + idx + 4);
    *(float4*)(swt + idx)     = *(const float4*)(Wfc + idx);
    *(float4*)(swt + idx + 4) = *(const float4*)(Wfc + idx + 4);
    __syncthreads();

    int nl = t >> 4;
    int o = t & 15;
    float acc = bfc[o];
    const float* er = se + nl * 128;
#pragma unroll 8
    for (int k = 0; k < 128; ++k)
        acc += er[k] * swt[k * 16 + o];

    float m = acc;
#pragma unroll
    for (int d = 1; d < 16; d <<= 1) m = fmaxf(m, __shfl_xor(m, d, 16));
    float e = expf(acc - m);
    float ssum = e;
#pragma unroll
    for (int d = 1; d < 16; d <<= 1) ssum += __shfl_xor(ssum, d, 16);
    out[(size_t)(nb + nl) * 16 + o] = (acc - m) - logf(ssum);
}

extern "C" void kernel_launch(void* const* d_in, const int* in_sizes, int n_in,
                              void* d_out, int out_size, void* d_ws, size_t ws_size,
                              hipStream_t stream) {
    const float* x   = (const float*)d_in[0];
    const int*   ei  = (const int*)d_in[1];
    const float* Wn0 = (const float*)d_in[2];
    const float* Ws0 = (const float*)d_in[3];
    const float* b0  = (const float*)d_in[4];
    const float* Wn1 = (const float*)d_in[5];
    const float* Ws1 = (const float*)d_in[6];
    const float* b1  = (const float*)d_in[7];
    const float* Wn2 = (const float*)d_in[8];
    const float* Ws2 = (const float*)d_in[9];
    const float* b2  = (const float*)d_in[10];
    const float* Wfc = (const float*)d_in[11];
    const float* bfc = (const float*)d_in[12];

    const int* src = ei;
    const int* dst = ei + NE;

    float* emb_out = (float*)d_out;
    float* lsm_out = emb_out + (size_t)NN * 128;

    char* ws = (char*)d_ws;
    _Float16*     xh     = (_Float16*)(ws);                    //  25,600,000 B
    _Float16*     hA     = (_Float16*)(ws + 25600000);         //  25,600,000 B
    _Float16*     hB     = (_Float16*)(ws + 51200000);         //  25,600,000 B
    _Float16*     mean   = (_Float16*)(ws + 76800000);         //  25,600,000 B
    int*          segcnt = (int*)     (ws + 102400000);        //      16,000 B
    int*          offs   = (int*)     (ws + 102416000);        //     400,004 B
    unsigned int* binbuf = (unsigned int*)(ws + 102816064);    //  10,240,000 B
    int*          csr    = (int*)     (ws + 113056064);        //   6,400,000 B
    _Float16*     wfrag  = (_Float16*)(ws + 119456064);        //     393,216 B (ends ~119.8 MB)

    // ---- prep: bins -> CSR, cast x, frag weights ----
    hipMemsetAsync(segcnt, 0, SEGTOT * sizeof(int), stream);
    k_binA<<<(NE + 255) / 256, 256, 0, stream>>>(src, dst, segcnt, binbuf);
    k_xcast<<<(NN * DD / 8) / 256, 256, 0, stream>>>(x, xh);
    k_wprep<<<384, 256, 0, stream>>>(Wn0, Ws0, Wn1, Ws1, Wn2, Ws2, wfrag);
    k_binB<<<NB, 256, 0, stream>>>(segcnt, binbuf, offs, csr);

    const int agg_blocks  = (NN + 3) / 4;       // 25000
    const int gemm_blocks = (NN + 63) / 64;     // 1563
    _Float16* wf0 = wfrag;
    _Float16* wf1 = wfrag + 4 * FRAG_ELEMS;
    _Float16* wf2 = wfrag + 8 * FRAG_ELEMS;

    // layer 0: xh -> hA (relu)
    k_agg<<<agg_blocks, 256, 0, stream>>>(xh, offs, csr, mean);
    k_gemm<<<gemm_blocks, 256, 0, stream>>>(mean, xh, wf0, b0, hA, nullptr);

    // layer 1: hA -> hB (relu)
    k_agg<<<agg_blocks, 256, 0, stream>>>(hA, offs, csr, mean);
    k_gemm<<<gemm_blocks, 256, 0, stream>>>(mean, hA, wf1, b1, hB, nullptr);

    // layer 2: hB -> emb fp32 (no relu)
    k_agg<<<agg_blocks, 256, 0, stream>>>(hB, offs, csr, mean);
    k_gemm<<<gemm_blocks, 256, 0, stream>>>(mean, hB, wf2, b2, nullptr, emb_out);

    // fc + log_softmax
    k_fc<<<NN / 16, 256, 0, stream>>>(emb_out, Wfc, bfc, lsm_out);
}